// Round 6
// baseline (731.319 us; speedup 1.0000x reference)
//
#include <hip/hip_runtime.h>
#include <hip/hip_bf16.h>

typedef __hip_bfloat16 bf16;
typedef short short8 __attribute__((ext_vector_type(8)));
typedef float f32x4 __attribute__((ext_vector_type(4)));

#define NB 2
#define NC 256
#define NH 120
#define NW 240
#define NHW (NH*NW)      // 28800
#define NSP 16384        // padded spectral pixels per image (128*128)
#define NHID 512
#define REPS 1e-5f
#define SC_W 0.06454972243679028f   // 1/sqrt(240)
#define SC_H 0.09128709291752769f   // 1/sqrt(120)
#define PI2 6.283185307179586f

__device__ __forceinline__ float gelu_f(float x){ return 0.5f*x*(1.f+erff(x*0.7071067811865476f)); }
__device__ __forceinline__ float us2f(ushort u){ union{float f; uint v;} c; c.v=((uint)u)<<16; return c.f; }
__device__ __forceinline__ ushort f2us(float f){ bf16 b=__float2bfloat16(f); return *(ushort*)&b; }

// ---- workspace float offsets ----
#define OFF_A0   0
#define OFF_D0   512
#define OFF_A1c  1024
#define OFF_D1c  1536
#define OFF_TWF  2048       // bf16[256][256] fwd-W DFT
#define OFF_THF  34816      // bf16[256][256] fwd-H
#define OFF_THI  67584      // bf16[256][256] inv-H
#define OFF_TWI  100352     // bf16[256][256] inv-W real
#define OFF_WRT  133120     // bf16[256][256] w_spec_r^T [o][i]
#define OFF_WIT  165888     // bf16[256][256] w_spec_i^T
#define OFF_IWB  198656     // bf16[256][256] inner_w [o][i]
#define OFF_W2B  231424     // bf16[256][512]
#define OFF_W1P  296960     // bf16[2][512][256]  a1-folded mlp_w1
#define OFF_B1P  428032     // f32[2][512]        folded bias1
#define OFF_PS   429056     // f32[2][450][512]   stats partials (sum | sumsq)
#define OFF_RA   889856     // 8388608 floats ping A
#define OFF_RB   9278464    // 8388608 floats ping B
#define WS_FLOATS 17667072ULL   // 70.7 MB

#define RA0 OFF_RA
#define RA1 (OFF_RA+4194304)
#define RB0 OFF_RB
#define RB1 (OFF_RB+4194304)
#define OFF_FRE RB0
#define OFF_FIM (RB0+3932160)

// ---------------- setup: DFT matrices + weight casts ----------------
__global__ __launch_bounds__(256) void k_setup(float* ws, const float* wsr, const float* wsi,
                                               const float* iw, const float* w2){
  int t = blockIdx.x*256 + threadIdx.x;
  if (t < 65536){ // TWF [n][w]
    int n=t>>8, w=t&255; float v=0.f;
    if(w<NW){
      if(n<121){ v = cosf(PI2*(float)((n*w)%NW)/(float)NW)*SC_W; }
      else if(n>=128 && n<249){ int k=n-128; v = -sinf(PI2*(float)((k*w)%NW)/(float)NW)*SC_W; }
    }
    ((ushort*)(ws+OFF_TWF))[t]=f2us(v); return;
  } t-=65536;
  if (t < 65536){ // THF
    int n=t>>8, j=t&255; float v=0.f;
    int h = j&127; bool im = (j>=128);
    if(h<NH){
      if(n<128){ int m=n; if(m<NH){ float sn,cs; sincosf(PI2*(float)((m*h)%NH)/(float)NH,&sn,&cs);
        v = (im? sn : cs)*SC_H; } }
      else { int m=n-128; if(m<NH){ float sn,cs; sincosf(PI2*(float)((m*h)%NH)/(float)NH,&sn,&cs);
        v = (im? cs : -sn)*SC_H; } }
    }
    ((ushort*)(ws+OFF_THF))[t]=f2us(v); return;
  } t-=65536;
  if (t < 65536){ // THI
    int n=t>>8, j=t&255; float v=0.f;
    int m = j&127; bool im = (j>=128);
    if(m<NH){
      if(n<128){ int h=n; if(h<NH){ float sn,cs; sincosf(PI2*(float)((h*m)%NH)/(float)NH,&sn,&cs);
        v = (im? -sn : cs)*SC_H; } }
      else { int h=n-128; if(h<NH){ float sn,cs; sincosf(PI2*(float)((h*m)%NH)/(float)NH,&sn,&cs);
        v = (im? cs : sn)*SC_H; } }
    }
    ((ushort*)(ws+OFF_THI))[t]=f2us(v); return;
  } t-=65536;
  if (t < 65536){ // TWI
    int w=t>>8, j=t&255; float v=0.f;
    if(w<NW){
      int k = j&127; bool im = (j>=128);
      if(k<121){
        float ck = (k==0||k==120)? 1.f : 2.f;
        float sn,cs; sincosf(PI2*(float)((w*k)%NW)/(float)NW,&sn,&cs);
        v = ck*(im? -sn : cs)*SC_W;
      }
    }
    ((ushort*)(ws+OFF_TWI))[t]=f2us(v); return;
  } t-=65536;
  if (t < 65536){ int o=t>>8,i=t&255; ((ushort*)(ws+OFF_WRT))[t]=f2us(wsr[i*NC+o]); return; } t-=65536;
  if (t < 65536){ int o=t>>8,i=t&255; ((ushort*)(ws+OFF_WIT))[t]=f2us(wsi[i*NC+o]); return; } t-=65536;
  if (t < 65536){ ((ushort*)(ws+OFF_IWB))[t]=f2us(iw[t]); return; } t-=65536;
  if (t < 131072){ ((ushort*)(ws+OFF_W2B))[t]=f2us(w2[t]); return; }
}

// ---------------- instance-norm stats on x ----------------
__global__ __launch_bounds__(256) void k_stats0(const float* x, const float* n0w, const float* n0b, float* ws){
  int g = blockIdx.x, c = g & (NC-1);
  const float4* xp = (const float4*)(x + (size_t)g*NHW);
  float s=0.f, q=0.f;
  for(int i=threadIdx.x;i<NHW/4;i+=256){
    float4 v=xp[i];
    s+=v.x+v.y+v.z+v.w;
    q=fmaf(v.x,v.x,fmaf(v.y,v.y,fmaf(v.z,v.z,fmaf(v.w,v.w,q))));
  }
  __shared__ float ls[4], lq[4];
  #pragma unroll
  for(int o=32;o>0;o>>=1){ s+=__shfl_down(s,o,64); q+=__shfl_down(q,o,64); }
  int lane=threadIdx.x&63, wid=threadIdx.x>>6;
  if(!lane){ ls[wid]=s; lq[wid]=q; }
  __syncthreads();
  if(!threadIdx.x){
    s=ls[0]+ls[1]+ls[2]+ls[3]; q=lq[0]+lq[1]+lq[2]+lq[3];
    float m=s*(1.f/NHW), var=q*(1.f/NHW)-m*m;
    float r=rsqrtf(var+REPS);
    float a=r*n0w[c];
    ws[OFF_A0+g]=a; ws[OFF_D0+g]=fmaf(-m,a,n0b[c]);
  }
}

// ---------------- norm+cast: x -> A1 bf16 [g][h][256] ----------------
__global__ __launch_bounds__(256) void k_norm(const float* x, float* ws){
  int h = blockIdx.x, g = blockIdx.y, t = threadIdx.x;
  float a = ws[OFF_A0+g], d = ws[OFF_D0+g];
  ushort v = 0;
  if(t < NW) v = f2us(fmaf(a, x[(size_t)g*NHW + (size_t)h*NW + t], d));
  ((ushort*)(ws+RA0))[(size_t)g*30720 + (size_t)h*256 + t] = v;
}

// ---------------- spectral GEMM ----------------
template<int SPLIT, int EPI>
__global__ __launch_bounds__(256) void k_sgemm(const ushort* Ap0, const ushort* Ap1, const ushort* Bm,
                                               ushort* O0, ushort* O1, ushort* Ub){
  int nb = blockIdx.x*64, mb = blockIdx.y*256;
  int tid = threadIdx.x, w = tid>>6, l = tid&63, lq = l>>4, lr = l&15;
  const ushort* ar0[4]; const ushort* ar1[4]; const ushort* br[4];
  #pragma unroll
  for(int mt=0;mt<4;mt++){
    size_t r = mb + w*64 + mt*16 + lr;
    ar0[mt] = Ap0 + r*(SPLIT?128:256) + lq*8;
    ar1[mt] = SPLIT ? (Ap1 + r*128 + lq*8) : ar0[mt];
  }
  #pragma unroll
  for(int nt=0;nt<4;nt++) br[nt] = Bm + (size_t)(nb + nt*16 + lr)*256 + lq*8;
  f32x4 acc[4][4] = {};
  #pragma unroll
  for(int kk=0;kk<8;kk++){
    int k = kk*32;
    short8 af[4], bfr[4];
    #pragma unroll
    for(int mt=0;mt<4;mt++){
      const ushort* p = SPLIT ? ((k<128 ? ar0[mt] : ar1[mt]) + (k&127)) : (ar0[mt] + k);
      af[mt] = *(const short8*)p;
    }
    #pragma unroll
    for(int nt=0;nt<4;nt++) bfr[nt] = *(const short8*)(br[nt]+k);
    #pragma unroll
    for(int mt=0;mt<4;mt++)
      #pragma unroll
      for(int nt=0;nt<4;nt++)
        acc[mt][nt] = __builtin_amdgcn_mfma_f32_16x16x32_bf16(af[mt], bfr[nt], acc[mt][nt], 0,0,0);
  }
  #pragma unroll
  for(int mt=0;mt<4;mt++){
    #pragma unroll
    for(int r=0;r<4;r++){
      int m = mb + w*64 + mt*16 + lq*4 + r;
      #pragma unroll
      for(int nt=0;nt<4;nt++){
        int n = nb + nt*16 + lr;
        float v = acc[mt][nt][r];
        if (EPI==0){
          if(n<128) O0[(size_t)m*128+n] = f2us(v);
          else      O1[(size_t)m*128+n-128] = f2us(v);
        } else {
          int g = m>>7, h = m&127;
          if(h<NH && n<NW) Ub[(size_t)g*NHW + (size_t)h*NW + n] = f2us(v);
        }
      }
    }
  }
}

// ---------------- dual-plane 64x64 bf16 transpose within 128-stride planes ----------------
__global__ __launch_bounds__(256) void k_t64d(const ushort* s0, ushort* d0, const ushort* s1, ushort* d1,
                                              int srows, int sgstr){
  __shared__ ushort lt[64][72];
  int z = blockIdx.z, g = z & 511;
  const ushort* src = (z>=512)? s1 : s0;
  ushort* dst = (z>=512)? d1 : d0;
  int i0=blockIdx.y*64, p0=blockIdx.x*64;
  int t=threadIdx.x, r=t>>2, q=t&3;
  int row = i0 + r;
  uint4 u0=make_uint4(0,0,0,0), u1=u0;
  if(row < srows){
    const ushort* sp = src + (size_t)g*sgstr + (size_t)row*128 + p0 + q*16;
    u0=*(const uint4*)sp; u1=*(const uint4*)(sp+8);
  }
  *(uint4*)&lt[r][q*16]=u0; *(uint4*)&lt[r][q*16+8]=u1;
  __syncthreads();
  int pr=t>>2, q2=t&3;
  union { ushort s[8]; uint4 u; } o0, o1;
  #pragma unroll
  for(int e=0;e<8;e++){ o0.s[e]=lt[q2*16+e][pr]; o1.s[e]=lt[q2*16+8+e][pr]; }
  ushort* dp = dst + (size_t)g*NSP + (size_t)(p0+pr)*128 + i0 + q2*16;
  *(uint4*)dp = o0.u; *(uint4*)(dp+8) = o1.u;
}

// ---------------- dual-plane pixel transpose: [b][c:256][NSP] -> [b][NSP][c] ----------------
__global__ __launch_bounds__(256) void k_tPd(const ushort* s0, ushort* d0, const ushort* s1, ushort* d1){
  __shared__ ushort lt[64][72];
  int z=blockIdx.z, b=z&1;
  const ushort* src = (z>=2)? s1 : s0;
  ushort* dst = (z>=2)? d1 : d0;
  int i0=blockIdx.y*64, p0=blockIdx.x*64;
  int t=threadIdx.x, r=t>>2, q=t&3;
  const ushort* sp = src + (size_t)(b*NC+i0+r)*NSP + p0 + q*16;
  uint4 u0=*(const uint4*)sp, u1=*(const uint4*)(sp+8);
  *(uint4*)&lt[r][q*16]=u0; *(uint4*)&lt[r][q*16+8]=u1;
  __syncthreads();
  int pr=t>>2, q2=t&3;
  union { ushort s[8]; uint4 u; } o0, o1;
  #pragma unroll
  for(int e=0;e<8;e++){ o0.s[e]=lt[q2*16+e][pr]; o1.s[e]=lt[q2*16+8+e][pr]; }
  ushort* dp = dst + ((size_t)b*NSP + p0 + pr)*NC + i0 + q2*16;
  *(uint4*)dp = o0.u; *(uint4*)(dp+8) = o1.u;
}

// ---------------- complex spectral mix via MFMA ----------------
__global__ __launch_bounds__(256) void k_mixg(float* ws){
  int b = blockIdx.z, p0 = blockIdx.x*32;
  int tid = threadIdx.x, w = tid>>6, l = tid&63, lq = l>>4, lr = l&15;
  const ushort* Wr = (const ushort*)(ws+OFF_WRT);
  const ushort* Wi = (const ushort*)(ws+OFF_WIT);
  const ushort* Gr = (const ushort*)(ws+RA0) + (size_t)b*NSP*NC;
  const ushort* Gi = (const ushort*)(ws+RA1) + (size_t)b*NSP*NC;
  const ushort *wrr[4], *wir[4], *brr[2], *bir[2];
  #pragma unroll
  for(int mt=0;mt<4;mt++){ size_t ro=(size_t)(w*64+mt*16+lr)*NC+lq*8; wrr[mt]=Wr+ro; wir[mt]=Wi+ro; }
  #pragma unroll
  for(int nt=0;nt<2;nt++){ size_t ro=(size_t)(p0+nt*16+lr)*NC+lq*8; brr[nt]=Gr+ro; bir[nt]=Gi+ro; }
  f32x4 aR[4][2]={}, aI[4][2]={};
  for(int k=0;k<256;k+=32){
    short8 fr[4], fi[4], fin[4], gr[2], gi[2];
    #pragma unroll
    for(int mt=0;mt<4;mt++){
      fr[mt]=*(const short8*)(wrr[mt]+k);
      fi[mt]=*(const short8*)(wir[mt]+k);
      union { short8 s; uint u[4]; } nv; nv.s=fi[mt];
      nv.u[0]^=0x80008000u; nv.u[1]^=0x80008000u; nv.u[2]^=0x80008000u; nv.u[3]^=0x80008000u;
      fin[mt]=nv.s;
    }
    #pragma unroll
    for(int nt=0;nt<2;nt++){ gr[nt]=*(const short8*)(brr[nt]+k); gi[nt]=*(const short8*)(bir[nt]+k); }
    #pragma unroll
    for(int mt=0;mt<4;mt++)
      #pragma unroll
      for(int nt=0;nt<2;nt++){
        aR[mt][nt]=__builtin_amdgcn_mfma_f32_16x16x32_bf16(fr[mt], gr[nt], aR[mt][nt],0,0,0);
        aR[mt][nt]=__builtin_amdgcn_mfma_f32_16x16x32_bf16(fin[mt],gi[nt], aR[mt][nt],0,0,0);
        aI[mt][nt]=__builtin_amdgcn_mfma_f32_16x16x32_bf16(fi[mt], gr[nt], aI[mt][nt],0,0,0);
        aI[mt][nt]=__builtin_amdgcn_mfma_f32_16x16x32_bf16(fr[mt], gi[nt], aI[mt][nt],0,0,0);
      }
  }
  ushort* Yre = (ushort*)(ws+RB0);
  ushort* Yim = (ushort*)(ws+RB1);
  #pragma unroll
  for(int mt=0;mt<4;mt++){
    #pragma unroll
    for(int r=0;r<4;r++){
      int m = w*64 + mt*16 + lq*4 + r;
      #pragma unroll
      for(int nt=0;nt<2;nt++){
        int n = p0 + nt*16 + lr;
        size_t ad = (size_t)(b*NC+m)*NSP + n;
        Yre[ad] = f2us(aR[mt][nt][r]);
        Yim[ad] = f2us(aI[mt][nt][r]);
      }
    }
  }
}

// ---------------- Phase A: fused x-transpose + inner conv + gelu + stats + U' ----------------
// 512 threads, 128-pixel tile; 8 waves: (w&3)=m-quarter, (w>>2)=pixel-half
__global__ __launch_bounds__(512,4) void k_inner(float* ws, const float* x, const float* ib){
  __shared__ ushort xt[128*264];
  int b = blockIdx.z, blk = blockIdx.x, p0 = blk*128;
  int t = threadIdx.x, w = t>>6, l = t&63, lq = l>>4, lr = l&15;
  // load + transpose x tile -> xt[p][c] bf16 (stride 264)
  #pragma unroll 4
  for(int cc=0; cc<16; cc++){
    int c = cc*16 + (t>>5);
    int p4 = (t&31)*4;
    float4 v = *(const float4*)(x + ((size_t)(b*NC+c))*NHW + p0 + p4);
    xt[(p4  )*264+c]=f2us(v.x); xt[(p4+1)*264+c]=f2us(v.y);
    xt[(p4+2)*264+c]=f2us(v.z); xt[(p4+3)*264+c]=f2us(v.w);
  }
  __syncthreads();
  const ushort* W = (const ushort*)(ws+OFF_IWB);
  int mw = w&3, ph = (w>>2)*64;
  const ushort* ar[4];
  #pragma unroll
  for(int mt=0;mt<4;mt++) ar[mt] = W + (size_t)(mw*64+mt*16+lr)*256 + lq*8;
  f32x4 acc[4][4] = {};
  #pragma unroll
  for(int kk=0;kk<8;kk++){
    int k = kk*32;
    short8 af[4], bfr[4];
    #pragma unroll
    for(int mt=0;mt<4;mt++) af[mt] = *(const short8*)(ar[mt]+k);
    #pragma unroll
    for(int nt=0;nt<4;nt++) bfr[nt] = *(const short8*)&xt[(ph+nt*16+lr)*264 + k + lq*8];
    #pragma unroll
    for(int mt=0;mt<4;mt++)
      #pragma unroll
      for(int nt=0;nt<4;nt++)
        acc[mt][nt] = __builtin_amdgcn_mfma_f32_16x16x32_bf16(af[mt], bfr[nt], acc[mt][nt], 0,0,0);
  }
  __syncthreads();   // all waves done reading xt; reuse as output transpose buffer
  const ushort* Usp = (const ushort*)(ws+OFF_RA);
  float* PS = ws + OFF_PS + ((size_t)(b*450 + blk*2 + (w>>2)))*512;
  #pragma unroll
  for(int mt=0;mt<4;mt++){
    #pragma unroll
    for(int r=0;r<4;r++){
      int m = mw*64 + mt*16 + lq*4 + r;
      float bb = ib[m];
      float ss = 0.f, sq = 0.f;
      #pragma unroll
      for(int nt=0;nt<4;nt++){
        int pl = ph + nt*16 + lr;
        int n = p0 + pl;
        float uv = us2f(Usp[((size_t)(b*NC+m))*NHW + n]);
        float g = gelu_f(acc[mt][nt][r] + bb + uv);
        xt[pl*264 + m] = f2us(g);
        ss += g; sq = fmaf(g,g,sq);
      }
      #pragma unroll
      for(int ofs=1; ofs<16; ofs<<=1){ ss += __shfl_xor(ss, ofs, 64); sq += __shfl_xor(sq, ofs, 64); }
      if(lr==0){ PS[m] = ss; PS[256+m] = sq; }
    }
  }
  __syncthreads();
  ushort* Up = (ushort*)(ws+OFF_RB);
  {
    int p = t>>2, c0 = (t&3)*64;
    const ushort* sp = &xt[p*264 + c0];
    ushort* dp = Up + ((size_t)(b*NHW + p0 + p))*256 + c0;
    #pragma unroll
    for(int e=0;e<8;e++) ((uint4*)dp)[e] = ((const uint4*)sp)[e];
  }
}

// ---------------- stats1: reduce partials -> a1,d1 (FiLM folded) ----------------
__global__ __launch_bounds__(256) void k_stats1p(const float* gamma, const float* beta,
                                                 const float* n1w, const float* n1b, float* ws){
  int g = blockIdx.x, b = g>>8, c = g&255;
  float s=0.f, q=0.f;
  for(int i=threadIdx.x;i<450;i+=256){
    const float* P = ws + OFF_PS + ((size_t)(b*450+i))*512;
    s += P[c]; q += P[256+c];
  }
  __shared__ float ls[4], lq2[4];
  #pragma unroll
  for(int o=32;o>0;o>>=1){ s+=__shfl_down(s,o,64); q+=__shfl_down(q,o,64); }
  int lane=threadIdx.x&63, wid=threadIdx.x>>6;
  if(!lane){ ls[wid]=s; lq2[wid]=q; }
  __syncthreads();
  if(!threadIdx.x){
    s=ls[0]+ls[1]+ls[2]+ls[3]; q=lq2[0]+lq2[1]+lq2[2]+lq2[3];
    float m=s*(1.f/NHW), var=q*(1.f/NHW)-m*m;
    float r=rsqrtf(var+REPS);
    float gp1 = 1.f + gamma[c];
    float wv = n1w[c];
    ws[OFF_A1c+g] = gp1*wv*r;
    ws[OFF_D1c+g] = gp1*(n1b[c] - m*r*wv) + beta[c];
  }
}

// ---------------- fold a1/d1 into W1: W1'[b]=W1*diag(a1), b1'=W1*d1+b1 ----------------
__global__ __launch_bounds__(64) void k_fold(float* ws, const float* w1, const float* b1){
  int o = blockIdx.x, b = blockIdx.y, t = threadIdx.x;
  float acc = 0.f;
  ushort* W1p = (ushort*)(ws+OFF_W1P);
  #pragma unroll
  for(int ii=0; ii<4; ii++){
    int i = ii*64 + t;
    float wv = w1[o*256+i];
    W1p[((size_t)(b*NHID+o))*256 + i] = f2us(wv * ws[OFF_A1c + b*NC + i]);
    acc = fmaf(wv, ws[OFF_D1c + b*NC + i], acc);
  }
  #pragma unroll
  for(int ofs=32; ofs; ofs>>=1) acc += __shfl_down(acc, ofs, 64);
  if(!t) ws[OFF_B1P + b*NHID + o] = acc + b1[o];
}

// ---------------- Phase C: fused mlp1+gelu+mlp2+residual ----------------
// 512 threads, 64-pixel tile. LDS: phase0 = Up staging [64][264]; phase1+ = midT [64][520]
__global__ __launch_bounds__(512,4) void k_mlp(float* ws, const float* x, const float* b2, float* out){
  __shared__ ushort lds[66560];
  int b = blockIdx.z, p0 = blockIdx.x*64;
  int t = threadIdx.x, w = t>>6, l = t&63, lq = l>>4, lr = l&15;
  // stage Up tile -> lds [p][c] stride 264
  {
    int p = t>>3, c0 = (t&7)*32;
    const ushort* sp = (const ushort*)(ws+OFF_RB) + ((size_t)(b*NHW + p0 + p))*256 + c0;
    uint4 v0=((const uint4*)sp)[0], v1=((const uint4*)sp)[1], v2=((const uint4*)sp)[2], v3=((const uint4*)sp)[3];
    ushort* dp = &lds[p*264 + c0];
    ((uint4*)dp)[0]=v0; ((uint4*)dp)[1]=v1; ((uint4*)dp)[2]=v2; ((uint4*)dp)[3]=v3;
  }
  __syncthreads();
  const ushort* W1p = (const ushort*)(ws+OFF_W1P) + (size_t)b*NHID*256;
  const ushort* ar[4];
  #pragma unroll
  for(int mt=0;mt<4;mt++) ar[mt] = W1p + (size_t)(w*64+mt*16+lr)*256 + lq*8;
  f32x4 acc1[4][4] = {};
  #pragma unroll
  for(int kk=0;kk<8;kk++){
    int k = kk*32;
    short8 af[4], bfr[4];
    #pragma unroll
    for(int mt=0;mt<4;mt++) af[mt] = *(const short8*)(ar[mt]+k);
    #pragma unroll
    for(int nt=0;nt<4;nt++) bfr[nt] = *(const short8*)&lds[(nt*16+lr)*264 + k + lq*8];
    #pragma unroll
    for(int mt=0;mt<4;mt++)
      #pragma unroll
      for(int nt=0;nt<4;nt++)
        acc1[mt][nt] = __builtin_amdgcn_mfma_f32_16x16x32_bf16(af[mt], bfr[nt], acc1[mt][nt], 0,0,0);
  }
  __syncthreads();   // done reading staging; overwrite as midT
  const float* b1p = ws + OFF_B1P + b*NHID;
  #pragma unroll
  for(int mt=0;mt<4;mt++){
    #pragma unroll
    for(int r=0;r<4;r++){
      int m1 = w*64 + mt*16 + lq*4 + r;
      float bb = b1p[m1];
      #pragma unroll
      for(int nt=0;nt<4;nt++){
        int p = nt*16 + lr;
        lds[p*520 + m1] = f2us(gelu_f(acc1[mt][nt][r] + bb));
      }
    }
  }
  __syncthreads();
  const ushort* W2 = (const ushort*)(ws+OFF_W2B);
  int mw = w&3, nh = (w>>2)*32;
  const ushort* a2[4];
  #pragma unroll
  for(int mt=0;mt<4;mt++) a2[mt] = W2 + (size_t)(mw*64+mt*16+lr)*512 + lq*8;
  f32x4 acc2[4][2] = {};
  #pragma unroll
  for(int kk=0;kk<16;kk++){
    int k = kk*32;
    short8 af[4], bfr[2];
    #pragma unroll
    for(int mt=0;mt<4;mt++) af[mt] = *(const short8*)(a2[mt]+k);
    #pragma unroll
    for(int nt=0;nt<2;nt++) bfr[nt] = *(const short8*)&lds[(nh+nt*16+lr)*520 + k + lq*8];
    #pragma unroll
    for(int mt=0;mt<4;mt++)
      #pragma unroll
      for(int nt=0;nt<2;nt++)
        acc2[mt][nt] = __builtin_amdgcn_mfma_f32_16x16x32_bf16(af[mt], bfr[nt], acc2[mt][nt], 0,0,0);
  }
  #pragma unroll
  for(int mt=0;mt<4;mt++){
    #pragma unroll
    for(int r=0;r<4;r++){
      int om = mw*64 + mt*16 + lq*4 + r;
      float bb = b2[om];
      #pragma unroll
      for(int nt=0;nt<2;nt++){
        int n = p0 + nh + nt*16 + lr;
        size_t ad = ((size_t)(b*NC+om))*NHW + n;
        out[ad] = acc2[mt][nt][r] + bb + x[ad];
      }
    }
  }
}

extern "C" void kernel_launch(void* const* d_in, const int* in_sizes, int n_in,
                              void* d_out, int out_size, void* d_ws, size_t ws_size,
                              hipStream_t stream) {
  const float* x     = (const float*)d_in[0];
  const float* gamma = (const float*)d_in[1];
  const float* beta  = (const float*)d_in[2];
  const float* n0w   = (const float*)d_in[3];
  const float* n0b   = (const float*)d_in[4];
  const float* n1w   = (const float*)d_in[5];
  const float* n1b   = (const float*)d_in[6];
  const float* wsr   = (const float*)d_in[7];
  const float* wsi   = (const float*)d_in[8];
  const float* iw    = (const float*)d_in[9];
  const float* ib    = (const float*)d_in[10];
  const float* w1    = (const float*)d_in[11];
  const float* b1    = (const float*)d_in[12];
  const float* w2    = (const float*)d_in[13];
  const float* b2    = (const float*)d_in[14];
  float* ws = (float*)d_ws;
  float* out = (float*)d_out;
  if (ws_size < WS_FLOATS*4ULL) return;

  k_setup <<<dim3(2304), dim3(256), 0, stream>>>(ws, wsr, wsi, iw, w2);
  k_stats0<<<dim3(512),  dim3(256), 0, stream>>>(x, n0w, n0b, ws);
  k_norm  <<<dim3(120,512), dim3(256), 0, stream>>>(x, ws);
  // GEMM1: A1(RA) -> F(RB planes)
  k_sgemm<0,0><<<dim3(4,240), dim3(256), 0, stream>>>((const ushort*)(ws+RA0), (const ushort*)(ws+RA0),
      (const ushort*)(ws+OFF_TWF), (ushort*)(ws+OFF_FRE), (ushort*)(ws+OFF_FIM), nullptr);
  // T1: F(RB) -> Ft(RA)  (both planes)
  k_t64d <<<dim3(2,2,1024), dim3(256), 0, stream>>>((const ushort*)(ws+OFF_FRE), (ushort*)(ws+RA0),
      (const ushort*)(ws+OFF_FIM), (ushort*)(ws+RA1), NH, NH*128);
  // GEMM2: Ft(RA) -> G(RB)
  k_sgemm<1,0><<<dim3(4,256), dim3(256), 0, stream>>>((const ushort*)(ws+RA0), (const ushort*)(ws+RA1),
      (const ushort*)(ws+OFF_THF), (ushort*)(ws+RB0), (ushort*)(ws+RB1), nullptr);
  // T2: G(RB) -> Gt(RA) [b][p][c]  (both planes)
  k_tPd <<<dim3(256,4,4), dim3(256), 0, stream>>>((const ushort*)(ws+RB0), (ushort*)(ws+RA0),
      (const ushort*)(ws+RB1), (ushort*)(ws+RA1));
  // mix: Gt(RA) -> Y(RB)
  k_mixg <<<dim3(512,1,2), dim3(256), 0, stream>>>(ws);
  // GEMM4: Y(RB) -> Z(RA)
  k_sgemm<1,0><<<dim3(4,256), dim3(256), 0, stream>>>((const ushort*)(ws+RB0), (const ushort*)(ws+RB1),
      (const ushort*)(ws+OFF_THI), (ushort*)(ws+RA0), (ushort*)(ws+RA1), nullptr);
  // T3: Z(RA) -> Zt(RB)  (both planes)
  k_t64d <<<dim3(2,2,1024), dim3(256), 0, stream>>>((const ushort*)(ws+RA0), (ushort*)(ws+RB0),
      (const ushort*)(ws+RA1), (ushort*)(ws+RB1), 128, NSP);
  // GEMM5: Zt(RB) -> U spectral bf16 channel-major (RA)
  k_sgemm<1,1><<<dim3(4,256), dim3(256), 0, stream>>>((const ushort*)(ws+RB0), (const ushort*)(ws+RB1),
      (const ushort*)(ws+OFF_TWI), nullptr, nullptr, (ushort*)(ws+RA0));
  // Phase A: inner conv fused (x + Usp -> U' pixel-major bf16 in RB, + stats partials)
  k_inner <<<dim3(225,1,2), dim3(512), 0, stream>>>(ws, x, ib);
  k_stats1p<<<dim3(512), dim3(256), 0, stream>>>(gamma, beta, n1w, n1b, ws);
  k_fold  <<<dim3(512,2), dim3(64), 0, stream>>>(ws, w1, b1);
  // Phase C: fused MLP
  k_mlp   <<<dim3(450,1,2), dim3(512), 0, stream>>>(ws, x, b2, out);
}